// Round 24
// baseline (71.359 us; speedup 1.0000x reference)
//
#include <hip/hip_runtime.h>

typedef _Float16 f16x8 __attribute__((ext_vector_type(8)));
typedef _Float16 f16x4 __attribute__((ext_vector_type(4)));
typedef float    f32x4 __attribute__((ext_vector_type(4)));

#define B_ 4
#define T_ 4096
#define C_ 768
#define H_ 64
#define BT_ (B_ * T_)
#define SCALE 0.03608439182435161f   // 768^-0.5

// ---------------------------------------------------------------------------
// W transpose+cast: Wt f16 [192][768] = [Wq^T | Wk^T | Wv^T] rows. 48 blocks.
// ---------------------------------------------------------------------------
__global__ __launch_bounds__(256) void wt_cast(
    const float* __restrict__ Wk,
    const float* __restrict__ Wq,
    const float* __restrict__ Wv,
    _Float16* __restrict__ Wt)
{
    __shared__ float Ws[16][192];
    const int tid = threadIdx.x;
    const int k0  = blockIdx.x * 16;
    for (int i = tid; i < 16 * 64; i += 256) {
        const int r = i >> 6, c = i & 63;
        Ws[r][c]       = Wq[(size_t)(k0 + r) * H_ + c];
        Ws[r][64 + c]  = Wk[(size_t)(k0 + r) * H_ + c];
        Ws[r][128 + c] = Wv[(size_t)(k0 + r) * H_ + c];
    }
    __syncthreads();
    for (int i = tid; i < 384; i += 256) {
        const int n = i >> 1, c8 = (i & 1) * 8;
        f16x8 o;
#pragma unroll
        for (int jj = 0; jj < 8; ++jj) o[jj] = (_Float16)Ws[c8 + jj][n];
        *(f16x8*)&Wt[(size_t)n * C_ + k0 + c8] = o;
    }
}

// ---------------------------------------------------------------------------
// QKV projection as MFMA GEMM: [16384 x 768] * [768 x 192].
// Double-buffered T14 async-split (round-14 win). BM=32, 256 threads,
// grid 512 (round-21's BM=64 regressed — do not re-apply).
// ---------------------------------------------------------------------------
__global__ __launch_bounds__(256, 2) void qkv_gemm(
    const float* __restrict__ x,
    const _Float16* __restrict__ Wt,
    _Float16* __restrict__ qh,
    _Float16* __restrict__ kh,
    _Float16* __restrict__ vtt)
{
    __shared__ _Float16 Ah[2][32][72];
    __shared__ _Float16 Bh[2][192][72];

    const int tid  = threadIdx.x;
    const int lane = tid & 63;
    const int w    = tid >> 6;
    const int l15  = lane & 15;
    const int l4   = lane >> 4;
    const int mbase = blockIdx.x * 32;

    const int arow = tid >> 3;
    const int acb  = (tid & 7) * 8;
    const float* asrc = &x[(size_t)(mbase + arow) * C_ + acb];

    f32x4 acc[2][3];
#pragma unroll
    for (int mr = 0; mr < 2; ++mr)
#pragma unroll
        for (int j = 0; j < 3; ++j) acc[mr][j] = (f32x4){0.f, 0.f, 0.f, 0.f};

    {   // prologue: stage k-slab 0 into buffer 0
        const float4 x0 = *(const float4*)(asrc);
        const float4 x1 = *(const float4*)(asrc + 4);
        f16x8 a = { (_Float16)x0.x, (_Float16)x0.y, (_Float16)x0.z, (_Float16)x0.w,
                    (_Float16)x1.x, (_Float16)x1.y, (_Float16)x1.z, (_Float16)x1.w };
        *(f16x8*)&Ah[0][arow][acb] = a;
#pragma unroll
        for (int r = 0; r < 6; ++r) {
            const int idx = tid + r * 256;
            const int n = idx >> 3, c8 = (idx & 7) * 8;
            *(f16x8*)&Bh[0][n][c8] = *(const f16x8*)&Wt[(size_t)n * C_ + c8];
        }
    }

    for (int it = 0; it < 12; ++it) {
        __syncthreads();                 // buf[cur] staged & visible
        const int cur = it & 1;
        const bool more = (it + 1 < 12);

        // ---- issue stage loads for slab it+1 (LDS writes after compute)
        f16x8 sa;
        f16x8 sb[6];
        if (more) {
            const int k0n = (it + 1) * 64;
            const float4 x0 = *(const float4*)(asrc + k0n);
            const float4 x1 = *(const float4*)(asrc + k0n + 4);
            sa = (f16x8){ (_Float16)x0.x, (_Float16)x0.y, (_Float16)x0.z, (_Float16)x0.w,
                          (_Float16)x1.x, (_Float16)x1.y, (_Float16)x1.z, (_Float16)x1.w };
#pragma unroll
            for (int r = 0; r < 6; ++r) {
                const int idx = tid + r * 256;
                const int n = idx >> 3, c8 = (idx & 7) * 8;
                sb[r] = *(const f16x8*)&Wt[(size_t)n * C_ + k0n + c8];
            }
        }
        __builtin_amdgcn_sched_barrier(0);   // pin load issue before compute

        // ---- compute slab it from buf[cur]
#pragma unroll
        for (int kk = 0; kk < 2; ++kk) {
            f16x8 af0 = *(const f16x8*)&Ah[cur][l15][kk * 32 + l4 * 8];
            f16x8 af1 = *(const f16x8*)&Ah[cur][16 + l15][kk * 32 + l4 * 8];
#pragma unroll
            for (int j = 0; j < 3; ++j) {
                const f16x8 bf =
                    *(const f16x8*)&Bh[cur][w * 48 + j * 16 + l15][kk * 32 + l4 * 8];
                acc[0][j] = __builtin_amdgcn_mfma_f32_16x16x32_f16(af0, bf, acc[0][j], 0, 0, 0);
                acc[1][j] = __builtin_amdgcn_mfma_f32_16x16x32_f16(af1, bf, acc[1][j], 0, 0, 0);
            }
        }

        // ---- write staged slab into the other buffer (vmcnt waits here)
        if (more) {
            const int nxt = cur ^ 1;
            *(f16x8*)&Ah[nxt][arow][acb] = sa;
#pragma unroll
            for (int r = 0; r < 6; ++r) {
                const int idx = tid + r * 256;
                const int n = idx >> 3, c8 = (idx & 7) * 8;
                *(f16x8*)&Bh[nxt][n][c8] = sb[r];
            }
        }
    }

#pragma unroll
    for (int mr = 0; mr < 2; ++mr) {
        const size_t row0 = mbase + mr * 16 + l4 * 4;
#pragma unroll
        for (int j = 0; j < 3; ++j) {
            const int gcol = w * 48 + j * 16;
            if (gcol < 64) {
                const int h = gcol + l15;
#pragma unroll
                for (int r = 0; r < 4; ++r)
                    qh[(row0 + r) * H_ + h] = (_Float16)(acc[mr][j][r] * SCALE);
            } else if (gcol < 128) {
                const int h = gcol - 64 + l15;
#pragma unroll
                for (int r = 0; r < 4; ++r)
                    kh[(row0 + r) * H_ + h] = (_Float16)acc[mr][j][r];
            } else {
                const int h = gcol - 128 + l15;
                f16x4 o = { (_Float16)acc[mr][j][0], (_Float16)acc[mr][j][1],
                            (_Float16)acc[mr][j][2], (_Float16)acc[mr][j][3] };
                *(f16x4*)&vtt[((row0 >> 6) << 12) + (h << 6) + (row0 & 63)] = o;
            }
        }
    }
}

// ---------------------------------------------------------------------------
// Flash attention (round-20/23 structure). THIS ROUND'S single change:
// per-qs Ps buffers (Ps[4][2][16][72], +9 KB LDS). The shared buffer forced
// write0 < read0 < write1 < read1 (WAR through same addresses), putting two
// full lgkmcnt roundtrips serially on the critical path; with disjoint
// buffers both writes issue together and the two PV MFMA chains interleave.
// LDS 54 KB -> 2 blocks/CU (occupancy changes in this range measured
// neutral, r15/r17). NOTE: launch_bounds stays (256,2) (round-5 spill).
// ---------------------------------------------------------------------------
__global__ __launch_bounds__(256, 2) void attn(
    const _Float16* __restrict__ qh,
    const _Float16* __restrict__ kh,
    const _Float16* __restrict__ vtt,
    float* __restrict__ out,
    _Float16* __restrict__ Op,
    float* __restrict__ Mlp)
{
    __shared__ _Float16 Ks[2][64][72];     // [buf][s_local][h]  (+8 pad)
    __shared__ _Float16 Vs[2][64][72];     // [buf][h][s_local]
    __shared__ _Float16 Ps[4][2][16][72];  // per-wave, PER-QS P scratch

    const int b = blockIdx.x / 144;
    const int j = 143 - (blockIdx.x - b * 144);   // heavy chunks first
    int k = 0;
    while (k < 7 && j >= 2 * (k + 1) * (k + 2)) ++k;
    const int local = j - 2 * k * (k + 1);
    const int qt = 4 * k + local / (k + 1);       // 128-row q-tile id
    const int c  = local - (local / (k + 1)) * (k + 1);
    const int nc = k + 1;
    const int qb = qt << 7;
    const int NT = 2 * qt + 2;                    // kv tiles (64 each)
    const int t0 = c * 8;
    const int t1 = min(NT, t0 + 8);

    const int tid  = threadIdx.x;
    const int lane = tid & 63;
    const int wid  = tid >> 6;
    const int l15  = lane & 15;
    const int l4   = lane >> 4;
    const size_t bt0 = (size_t)b * T_;
    const int qbw = qb + wid * 32;                // wave's 32 q-rows
    const int tmaxw = 2 * qt + (wid >> 1);        // last tile this wave needs

    f16x8 qf[2][2];
#pragma unroll
    for (int qs = 0; qs < 2; ++qs) {
        const size_t qrow = bt0 + qbw + qs * 16 + l15;
        qf[qs][0] = *(const f16x8*)&qh[qrow * H_ + l4 * 8];
        qf[qs][1] = *(const f16x8*)&qh[qrow * H_ + 32 + l4 * 8];
    }

    const int r0  = tid >> 3;
    const int c0b = (tid & 7) * 8;

    {   // prologue: stage tile t0 into buffer 0
        const size_t gb = (size_t)(bt0 + (t0 << 6)) * H_;
        *(f16x8*)&Ks[0][r0][c0b]      = *(const f16x8*)&kh[gb + r0 * 64 + c0b];
        *(f16x8*)&Ks[0][r0 + 32][c0b] = *(const f16x8*)&kh[gb + (r0 + 32) * 64 + c0b];
        *(f16x8*)&Vs[0][r0][c0b]      = *(const f16x8*)&vtt[gb + r0 * 64 + c0b];
        *(f16x8*)&Vs[0][r0 + 32][c0b] = *(const f16x8*)&vtt[gb + (r0 + 32) * 64 + c0b];
    }

    f32x4 O[2][4];
#pragma unroll
    for (int qs = 0; qs < 2; ++qs)
#pragma unroll
        for (int ht = 0; ht < 4; ++ht) O[qs][ht] = (f32x4){0.f, 0.f, 0.f, 0.f};
    float m[2] = {-1e30f, -1e30f};
    float l[2] = {0.f, 0.f};

    int cur = 0;
    for (int t = t0; t < t1; ++t) {
        __syncthreads();

        // issue stage loads for t+1 (written to LDS after compute)
        f16x8 sk0, sk1, sv0, sv1;
        const bool more = (t + 1 < t1);
        if (more) {
            const size_t gb = (size_t)(bt0 + ((t + 1) << 6)) * H_;
            sk0 = *(const f16x8*)&kh[gb + r0 * 64 + c0b];
            sk1 = *(const f16x8*)&kh[gb + (r0 + 32) * 64 + c0b];
            sv0 = *(const f16x8*)&vtt[gb + r0 * 64 + c0b];
            sv1 = *(const f16x8*)&vtt[gb + (r0 + 32) * 64 + c0b];
        }
        __builtin_amdgcn_sched_barrier(0);

        if (t <= tmaxw) {
            const int kb = t << 6;
            f16x8 kf[4][2], vf[4][2];
#pragma unroll
            for (int nt = 0; nt < 4; ++nt)
#pragma unroll
                for (int hf = 0; hf < 2; ++hf)
                    kf[nt][hf] = *(const f16x8*)&Ks[cur][nt * 16 + l15][hf * 32 + l4 * 8];
#pragma unroll
            for (int ht = 0; ht < 4; ++ht)
#pragma unroll
                for (int cc = 0; cc < 2; ++cc)
                    vf[ht][cc] = *(const f16x8*)&Vs[cur][ht * 16 + l15][cc * 32 + l4 * 8];

            const bool needMask = (kb + 63 > qbw);

            // ---- QK for BOTH q-subtiles: 16 independent MFMAs
            f32x4 st[2][4];
#pragma unroll
            for (int qs = 0; qs < 2; ++qs)
#pragma unroll
                for (int nt = 0; nt < 4; ++nt) {
                    f32x4 z = (f32x4){0.f, 0.f, 0.f, 0.f};
                    z = __builtin_amdgcn_mfma_f32_16x16x32_f16(kf[nt][0], qf[qs][0], z, 0, 0, 0);
                    st[qs][nt] = __builtin_amdgcn_mfma_f32_16x16x32_f16(kf[nt][1], qf[qs][1], z, 0, 0, 0);
                }
            if (needMask) {
#pragma unroll
                for (int qs = 0; qs < 2; ++qs) {
                    const int qpos = qbw + qs * 16 + l15;
                    const int sbase = kb + l4 * 4;
#pragma unroll
                    for (int nt = 0; nt < 4; ++nt)
#pragma unroll
                        for (int r = 0; r < 4; ++r)
                            if (sbase + nt * 16 + r > qpos) st[qs][nt][r] = -1e30f;
                }
            }

            // ---- softmax for BOTH subtiles (independent chains overlap)
            float mn[2], sf[2];
            f16x4 pv[2][4];
#pragma unroll
            for (int qs = 0; qs < 2; ++qs) {
                float mx = st[qs][0][0];
#pragma unroll
                for (int nt = 0; nt < 4; ++nt)
#pragma unroll
                    for (int r = 0; r < 4; ++r) mx = fmaxf(mx, st[qs][nt][r]);
                mx = fmaxf(mx, __shfl_xor(mx, 16));
                mx = fmaxf(mx, __shfl_xor(mx, 32));
                mn[qs] = fmaxf(m[qs], mx);
            }
#pragma unroll
            for (int qs = 0; qs < 2; ++qs) {
                sf[qs] = __expf(m[qs] - mn[qs]);
                float rs = 0.f;
#pragma unroll
                for (int nt = 0; nt < 4; ++nt)
#pragma unroll
                    for (int r = 0; r < 4; ++r) {
                        const float p = __expf(st[qs][nt][r] - mn[qs]);
                        rs += p;
                        pv[qs][nt][r] = (_Float16)p;
                    }
                rs += __shfl_xor(rs, 16);
                rs += __shfl_xor(rs, 32);
                l[qs] = l[qs] * sf[qs] + rs;
                m[qs] = mn[qs];
            }
            // ---- O-rescale for BOTH subtiles (shuffle chains overlap)
#pragma unroll
            for (int qs = 0; qs < 2; ++qs) {
                float sfO[4];
#pragma unroll
                for (int r = 0; r < 4; ++r) sfO[r] = __shfl(sf[qs], l4 * 4 + r);
#pragma unroll
                for (int ht = 0; ht < 4; ++ht)
#pragma unroll
                    for (int r = 0; r < 4; ++r) O[qs][ht][r] *= sfO[r];
            }

            // ---- Ps writes for BOTH qs (disjoint buffers -> both issue,
            //      one wait), then BOTH PV chains interleave
#pragma unroll
            for (int qs = 0; qs < 2; ++qs)
#pragma unroll
                for (int nt = 0; nt < 4; ++nt)
                    *(f16x4*)&Ps[wid][qs][l15][nt * 16 + l4 * 4] = pv[qs][nt];
#pragma unroll
            for (int qs = 0; qs < 2; ++qs) {
                const f16x8 pf0 = *(const f16x8*)&Ps[wid][qs][l15][l4 * 8];
                const f16x8 pf1 = *(const f16x8*)&Ps[wid][qs][l15][32 + l4 * 8];
#pragma unroll
                for (int ht = 0; ht < 4; ++ht) {
                    O[qs][ht] = __builtin_amdgcn_mfma_f32_16x16x32_f16(pf0, vf[ht][0], O[qs][ht], 0, 0, 0);
                    O[qs][ht] = __builtin_amdgcn_mfma_f32_16x16x32_f16(pf1, vf[ht][1], O[qs][ht], 0, 0, 0);
                }
            }
        }

        if (more) {
            const int nxt = cur ^ 1;
            *(f16x8*)&Ks[nxt][r0][c0b]      = sk0;
            *(f16x8*)&Ks[nxt][r0 + 32][c0b] = sk1;
            *(f16x8*)&Vs[nxt][r0][c0b]      = sv0;
            *(f16x8*)&Vs[nxt][r0 + 32][c0b] = sv1;
        }
        cur ^= 1;
    }

    // ---- epilogue: transport m/l to D-layout
    float mD[2][4], lD[2][4];
#pragma unroll
    for (int qs = 0; qs < 2; ++qs)
#pragma unroll
        for (int r = 0; r < 4; ++r) {
            mD[qs][r] = __shfl(m[qs], l4 * 4 + r);
            lD[qs][r] = __shfl(l[qs], l4 * 4 + r);
        }

    if (nc == 1) {
#pragma unroll
        for (int qs = 0; qs < 2; ++qs)
#pragma unroll
            for (int r = 0; r < 4; ++r) {
                const float inv = 1.f / lD[qs][r];
                const size_t row = bt0 + qbw + qs * 16 + l4 * 4 + r;
#pragma unroll
                for (int ht = 0; ht < 4; ++ht)
                    out[row * H_ + ht * 16 + l15] = O[qs][ht][r] * inv;
            }
    } else {
        const int slot = b * 144 + j;
#pragma unroll
        for (int qs = 0; qs < 2; ++qs) {
#pragma unroll
            for (int r = 0; r < 4; ++r) {
                const int grow = wid * 32 + qs * 16 + l4 * 4 + r;
#pragma unroll
                for (int ht = 0; ht < 4; ++ht)
                    Op[(size_t)slot * 8192 + grow * 64 + ht * 16 + l15] =
                        (_Float16)O[qs][ht][r];
            }
            if (l4 == 0) {
                const int grow = wid * 32 + qs * 16 + l15;
                Mlp[(size_t)slot * 256 + grow]       = m[qs];
                Mlp[(size_t)slot * 256 + 128 + grow] = l[qs];
            }
        }
    }
}

// ---------------------------------------------------------------------------
// Merge partial chunks for 128-row q-tiles with nc>=2 (qt >= 4).
// Grid 112 = 4 b x 28 qt.
// ---------------------------------------------------------------------------
__global__ __launch_bounds__(256) void attn_merge(
    const _Float16* __restrict__ Op,
    const float* __restrict__ Mlp,
    float* __restrict__ out)
{
    const int b  = blockIdx.x / 28;
    const int qt = 4 + (blockIdx.x - b * 28);
    const int k  = qt >> 2;
    const int g  = k + 1;                              // chunks: 2..8
    const int jstart = 2 * k * (k + 1) + (qt - 4 * k) * (k + 1);
    const int slot0  = b * 144 + jstart;

    const int tid  = threadIdx.x;
    const int colb = (tid & 7) * 8;

    for (int it = 0; it < 4; ++it) {
        const int row = it * 32 + (tid >> 3);
        float mf = -1e30f;
        for (int cc = 0; cc < g; ++cc)
            mf = fmaxf(mf, Mlp[(size_t)(slot0 + cc) * 256 + row]);
        float denom = 0.f;
        float acc[8];
#pragma unroll
        for (int jj = 0; jj < 8; ++jj) acc[jj] = 0.f;
        for (int cc = 0; cc < g; ++cc) {
            const float a = __expf(Mlp[(size_t)(slot0 + cc) * 256 + row] - mf);
            denom += a * Mlp[(size_t)(slot0 + cc) * 256 + 128 + row];
            const f16x8 o = *(const f16x8*)&Op[(size_t)(slot0 + cc) * 8192 + row * 64 + colb];
#pragma unroll
            for (int jj = 0; jj < 8; ++jj) acc[jj] += a * (float)o[jj];
        }
        const float inv = 1.f / denom;
        float* dst = &out[((size_t)b * T_ + (qt << 7) + row) * H_ + colb];
        float4 o0 = { acc[0] * inv, acc[1] * inv, acc[2] * inv, acc[3] * inv };
        float4 o1 = { acc[4] * inv, acc[5] * inv, acc[6] * inv, acc[7] * inv };
        *(float4*)dst = o0;
        *(float4*)(dst + 4) = o1;
    }
}

extern "C" void kernel_launch(void* const* d_in, const int* in_sizes, int n_in,
                              void* d_out, int out_size, void* d_ws, size_t ws_size,
                              hipStream_t stream) {
    const float* x  = (const float*)d_in[0];
    const float* Wk = (const float*)d_in[1];
    const float* Wq = (const float*)d_in[2];
    const float* Wv = (const float*)d_in[3];
    float* out = (float*)d_out;

    _Float16* qh  = (_Float16*)d_ws;                 // [B*T][H] (scaled)
    _Float16* kh  = qh + (size_t)BT_ * H_;           // [B*T][H]
    _Float16* vtt = kh + (size_t)BT_ * H_;           // [BT/64 tiles][64 h][64 s]
    _Float16* Wt  = vtt + (size_t)BT_ * H_;          // [192][768]
    _Float16* Op  = Wt + (size_t)192 * C_;           // 576 slots x [128][64] f16
    float*    Mlp = (float*)(Op + (size_t)576 * 8192);   // 576 x (m[128],l[128])

    wt_cast<<<dim3(48), dim3(256), 0, stream>>>(Wk, Wq, Wv, Wt);
    qkv_gemm<<<dim3(512), dim3(256), 0, stream>>>(x, Wt, qh, kh, vtt);
    attn<<<dim3(576), dim3(256), 0, stream>>>(qh, kh, vtt, out, Op, Mlp);
    attn_merge<<<dim3(112), dim3(256), 0, stream>>>(Op, Mlp, out);
}

// Round 25
// 70.927 us; speedup vs baseline: 1.0061x; 1.0061x over previous
//
#include <hip/hip_runtime.h>

typedef _Float16 f16x8 __attribute__((ext_vector_type(8)));
typedef _Float16 f16x4 __attribute__((ext_vector_type(4)));
typedef float    f32x4 __attribute__((ext_vector_type(4)));

#define B_ 4
#define T_ 4096
#define C_ 768
#define H_ 64
#define BT_ (B_ * T_)
#define SCALE 0.03608439182435161f   // 768^-0.5

// ---------------------------------------------------------------------------
// W transpose+cast: Wt f16 [192][768] = [Wq^T | Wk^T | Wv^T] rows. 48 blocks.
// ---------------------------------------------------------------------------
__global__ __launch_bounds__(256) void wt_cast(
    const float* __restrict__ Wk,
    const float* __restrict__ Wq,
    const float* __restrict__ Wv,
    _Float16* __restrict__ Wt)
{
    __shared__ float Ws[16][192];
    const int tid = threadIdx.x;
    const int k0  = blockIdx.x * 16;
    for (int i = tid; i < 16 * 64; i += 256) {
        const int r = i >> 6, c = i & 63;
        Ws[r][c]       = Wq[(size_t)(k0 + r) * H_ + c];
        Ws[r][64 + c]  = Wk[(size_t)(k0 + r) * H_ + c];
        Ws[r][128 + c] = Wv[(size_t)(k0 + r) * H_ + c];
    }
    __syncthreads();
    for (int i = tid; i < 384; i += 256) {
        const int n = i >> 1, c8 = (i & 1) * 8;
        f16x8 o;
#pragma unroll
        for (int jj = 0; jj < 8; ++jj) o[jj] = (_Float16)Ws[c8 + jj][n];
        *(f16x8*)&Wt[(size_t)n * C_ + k0 + c8] = o;
    }
}

// ---------------------------------------------------------------------------
// QKV projection as MFMA GEMM: [16384 x 768] * [768 x 192].
// Double-buffered T14 async-split (round-14 win): loads for k+1 issue right
// after the barrier, compute on buf[cur], ds_writes after. One barrier/step.
// BM=32, 256 threads, grid 512 (round-21's BM=64 regressed: 1 block/CU lost
// latency hiding — do not re-apply).
// ---------------------------------------------------------------------------
__global__ __launch_bounds__(256, 2) void qkv_gemm(
    const float* __restrict__ x,
    const _Float16* __restrict__ Wt,
    _Float16* __restrict__ qh,
    _Float16* __restrict__ kh,
    _Float16* __restrict__ vtt)
{
    __shared__ _Float16 Ah[2][32][72];
    __shared__ _Float16 Bh[2][192][72];

    const int tid  = threadIdx.x;
    const int lane = tid & 63;
    const int w    = tid >> 6;
    const int l15  = lane & 15;
    const int l4   = lane >> 4;
    const int mbase = blockIdx.x * 32;

    const int arow = tid >> 3;
    const int acb  = (tid & 7) * 8;
    const float* asrc = &x[(size_t)(mbase + arow) * C_ + acb];

    f32x4 acc[2][3];
#pragma unroll
    for (int mr = 0; mr < 2; ++mr)
#pragma unroll
        for (int j = 0; j < 3; ++j) acc[mr][j] = (f32x4){0.f, 0.f, 0.f, 0.f};

    {   // prologue: stage k-slab 0 into buffer 0
        const float4 x0 = *(const float4*)(asrc);
        const float4 x1 = *(const float4*)(asrc + 4);
        f16x8 a = { (_Float16)x0.x, (_Float16)x0.y, (_Float16)x0.z, (_Float16)x0.w,
                    (_Float16)x1.x, (_Float16)x1.y, (_Float16)x1.z, (_Float16)x1.w };
        *(f16x8*)&Ah[0][arow][acb] = a;
#pragma unroll
        for (int r = 0; r < 6; ++r) {
            const int idx = tid + r * 256;
            const int n = idx >> 3, c8 = (idx & 7) * 8;
            *(f16x8*)&Bh[0][n][c8] = *(const f16x8*)&Wt[(size_t)n * C_ + c8];
        }
    }

    for (int it = 0; it < 12; ++it) {
        __syncthreads();                 // buf[cur] staged & visible
        const int cur = it & 1;
        const bool more = (it + 1 < 12);

        // ---- issue stage loads for slab it+1 (LDS writes after compute)
        f16x8 sa;
        f16x8 sb[6];
        if (more) {
            const int k0n = (it + 1) * 64;
            const float4 x0 = *(const float4*)(asrc + k0n);
            const float4 x1 = *(const float4*)(asrc + k0n + 4);
            sa = (f16x8){ (_Float16)x0.x, (_Float16)x0.y, (_Float16)x0.z, (_Float16)x0.w,
                          (_Float16)x1.x, (_Float16)x1.y, (_Float16)x1.z, (_Float16)x1.w };
#pragma unroll
            for (int r = 0; r < 6; ++r) {
                const int idx = tid + r * 256;
                const int n = idx >> 3, c8 = (idx & 7) * 8;
                sb[r] = *(const f16x8*)&Wt[(size_t)n * C_ + k0n + c8];
            }
        }
        __builtin_amdgcn_sched_barrier(0);   // pin load issue before compute

        // ---- compute slab it from buf[cur]
#pragma unroll
        for (int kk = 0; kk < 2; ++kk) {
            f16x8 af0 = *(const f16x8*)&Ah[cur][l15][kk * 32 + l4 * 8];
            f16x8 af1 = *(const f16x8*)&Ah[cur][16 + l15][kk * 32 + l4 * 8];
#pragma unroll
            for (int j = 0; j < 3; ++j) {
                const f16x8 bf =
                    *(const f16x8*)&Bh[cur][w * 48 + j * 16 + l15][kk * 32 + l4 * 8];
                acc[0][j] = __builtin_amdgcn_mfma_f32_16x16x32_f16(af0, bf, acc[0][j], 0, 0, 0);
                acc[1][j] = __builtin_amdgcn_mfma_f32_16x16x32_f16(af1, bf, acc[1][j], 0, 0, 0);
            }
        }

        // ---- write staged slab into the other buffer (vmcnt waits here)
        if (more) {
            const int nxt = cur ^ 1;
            *(f16x8*)&Ah[nxt][arow][acb] = sa;
#pragma unroll
            for (int r = 0; r < 6; ++r) {
                const int idx = tid + r * 256;
                const int n = idx >> 3, c8 = (idx & 7) * 8;
                *(f16x8*)&Bh[nxt][n][c8] = sb[r];
            }
        }
    }

#pragma unroll
    for (int mr = 0; mr < 2; ++mr) {
        const size_t row0 = mbase + mr * 16 + l4 * 4;
#pragma unroll
        for (int j = 0; j < 3; ++j) {
            const int gcol = w * 48 + j * 16;
            if (gcol < 64) {
                const int h = gcol + l15;
#pragma unroll
                for (int r = 0; r < 4; ++r)
                    qh[(row0 + r) * H_ + h] = (_Float16)(acc[mr][j][r] * SCALE);
            } else if (gcol < 128) {
                const int h = gcol - 64 + l15;
#pragma unroll
                for (int r = 0; r < 4; ++r)
                    kh[(row0 + r) * H_ + h] = (_Float16)acc[mr][j][r];
            } else {
                const int h = gcol - 128 + l15;
                f16x4 o = { (_Float16)acc[mr][j][0], (_Float16)acc[mr][j][1],
                            (_Float16)acc[mr][j][2], (_Float16)acc[mr][j][3] };
                *(f16x4*)&vtt[((row0 >> 6) << 12) + (h << 6) + (row0 & 63)] = o;
            }
        }
    }
}

// ---------------------------------------------------------------------------
// Flash attention — the session's best measured configuration (rounds 20/23,
// 70.96-71.10 us total). LDS-staged double-buffered K/V, T14 async-split
// staging, chunks of <=8 kv-tiles -> 576 blocks heavy-first, swapped-QK
// lane-local softmax, BOTH q-subtile chains hoisted (QK x2, softmax x2,
// rescale x2, then Ps/PV x2) so long-latency chains overlap.
// Eliminated by measurement: per-qs Ps split (r24 neutral/−), setprio (r22
// 0), XCD swizzle (r18 −), defer-rescale/base-2 (r16 −), chunk=4 (r13/r17
// −), single-buffer (r15 0), V-from-global (r13 −), register prefetch
// (r8/r9 0), fused merge w/ fences (r11 −−), qkv BM=64 (r21 −).
// NOTE: launch_bounds min-waves/EU stays 2 (round-5 spill regression).
// ---------------------------------------------------------------------------
__global__ __launch_bounds__(256, 2) void attn(
    const _Float16* __restrict__ qh,
    const _Float16* __restrict__ kh,
    const _Float16* __restrict__ vtt,
    float* __restrict__ out,
    _Float16* __restrict__ Op,
    float* __restrict__ Mlp)
{
    __shared__ _Float16 Ks[2][64][72];   // [buf][s_local][h]  (+8 pad)
    __shared__ _Float16 Vs[2][64][72];   // [buf][h][s_local]
    __shared__ _Float16 Ps[4][16][72];   // per-wave P layout shuffle

    const int b = blockIdx.x / 144;
    const int j = 143 - (blockIdx.x - b * 144);   // heavy chunks first
    int k = 0;
    while (k < 7 && j >= 2 * (k + 1) * (k + 2)) ++k;
    const int local = j - 2 * k * (k + 1);
    const int qt = 4 * k + local / (k + 1);       // 128-row q-tile id
    const int c  = local - (local / (k + 1)) * (k + 1);
    const int nc = k + 1;
    const int qb = qt << 7;
    const int NT = 2 * qt + 2;                    // kv tiles (64 each)
    const int t0 = c * 8;
    const int t1 = min(NT, t0 + 8);

    const int tid  = threadIdx.x;
    const int lane = tid & 63;
    const int wid  = tid >> 6;
    const int l15  = lane & 15;
    const int l4   = lane >> 4;
    const size_t bt0 = (size_t)b * T_;
    const int qbw = qb + wid * 32;                // wave's 32 q-rows
    const int tmaxw = 2 * qt + (wid >> 1);        // last tile this wave needs

    f16x8 qf[2][2];
#pragma unroll
    for (int qs = 0; qs < 2; ++qs) {
        const size_t qrow = bt0 + qbw + qs * 16 + l15;
        qf[qs][0] = *(const f16x8*)&qh[qrow * H_ + l4 * 8];
        qf[qs][1] = *(const f16x8*)&qh[qrow * H_ + 32 + l4 * 8];
    }

    const int r0  = tid >> 3;
    const int c0b = (tid & 7) * 8;

    {   // prologue: stage tile t0 into buffer 0
        const size_t gb = (size_t)(bt0 + (t0 << 6)) * H_;
        *(f16x8*)&Ks[0][r0][c0b]      = *(const f16x8*)&kh[gb + r0 * 64 + c0b];
        *(f16x8*)&Ks[0][r0 + 32][c0b] = *(const f16x8*)&kh[gb + (r0 + 32) * 64 + c0b];
        *(f16x8*)&Vs[0][r0][c0b]      = *(const f16x8*)&vtt[gb + r0 * 64 + c0b];
        *(f16x8*)&Vs[0][r0 + 32][c0b] = *(const f16x8*)&vtt[gb + (r0 + 32) * 64 + c0b];
    }

    f32x4 O[2][4];
#pragma unroll
    for (int qs = 0; qs < 2; ++qs)
#pragma unroll
        for (int ht = 0; ht < 4; ++ht) O[qs][ht] = (f32x4){0.f, 0.f, 0.f, 0.f};
    float m[2] = {-1e30f, -1e30f};
    float l[2] = {0.f, 0.f};

    int cur = 0;
    for (int t = t0; t < t1; ++t) {
        __syncthreads();

        // issue stage loads for t+1 (written to LDS after compute)
        f16x8 sk0, sk1, sv0, sv1;
        const bool more = (t + 1 < t1);
        if (more) {
            const size_t gb = (size_t)(bt0 + ((t + 1) << 6)) * H_;
            sk0 = *(const f16x8*)&kh[gb + r0 * 64 + c0b];
            sk1 = *(const f16x8*)&kh[gb + (r0 + 32) * 64 + c0b];
            sv0 = *(const f16x8*)&vtt[gb + r0 * 64 + c0b];
            sv1 = *(const f16x8*)&vtt[gb + (r0 + 32) * 64 + c0b];
        }
        __builtin_amdgcn_sched_barrier(0);

        if (t <= tmaxw) {
            const int kb = t << 6;
            f16x8 kf[4][2], vf[4][2];
#pragma unroll
            for (int nt = 0; nt < 4; ++nt)
#pragma unroll
                for (int hf = 0; hf < 2; ++hf)
                    kf[nt][hf] = *(const f16x8*)&Ks[cur][nt * 16 + l15][hf * 32 + l4 * 8];
#pragma unroll
            for (int ht = 0; ht < 4; ++ht)
#pragma unroll
                for (int cc = 0; cc < 2; ++cc)
                    vf[ht][cc] = *(const f16x8*)&Vs[cur][ht * 16 + l15][cc * 32 + l4 * 8];

            const bool needMask = (kb + 63 > qbw);

            // ---- QK for BOTH q-subtiles: 16 independent MFMAs
            f32x4 st[2][4];
#pragma unroll
            for (int qs = 0; qs < 2; ++qs)
#pragma unroll
                for (int nt = 0; nt < 4; ++nt) {
                    f32x4 z = (f32x4){0.f, 0.f, 0.f, 0.f};
                    z = __builtin_amdgcn_mfma_f32_16x16x32_f16(kf[nt][0], qf[qs][0], z, 0, 0, 0);
                    st[qs][nt] = __builtin_amdgcn_mfma_f32_16x16x32_f16(kf[nt][1], qf[qs][1], z, 0, 0, 0);
                }
            if (needMask) {
#pragma unroll
                for (int qs = 0; qs < 2; ++qs) {
                    const int qpos = qbw + qs * 16 + l15;
                    const int sbase = kb + l4 * 4;
#pragma unroll
                    for (int nt = 0; nt < 4; ++nt)
#pragma unroll
                        for (int r = 0; r < 4; ++r)
                            if (sbase + nt * 16 + r > qpos) st[qs][nt][r] = -1e30f;
                }
            }

            // ---- softmax for BOTH subtiles (independent chains overlap)
            float mn[2], sf[2];
            f16x4 pv[2][4];
#pragma unroll
            for (int qs = 0; qs < 2; ++qs) {
                float mx = st[qs][0][0];
#pragma unroll
                for (int nt = 0; nt < 4; ++nt)
#pragma unroll
                    for (int r = 0; r < 4; ++r) mx = fmaxf(mx, st[qs][nt][r]);
                mx = fmaxf(mx, __shfl_xor(mx, 16));
                mx = fmaxf(mx, __shfl_xor(mx, 32));
                mn[qs] = fmaxf(m[qs], mx);
            }
#pragma unroll
            for (int qs = 0; qs < 2; ++qs) {
                sf[qs] = __expf(m[qs] - mn[qs]);
                float rs = 0.f;
#pragma unroll
                for (int nt = 0; nt < 4; ++nt)
#pragma unroll
                    for (int r = 0; r < 4; ++r) {
                        const float p = __expf(st[qs][nt][r] - mn[qs]);
                        rs += p;
                        pv[qs][nt][r] = (_Float16)p;
                    }
                rs += __shfl_xor(rs, 16);
                rs += __shfl_xor(rs, 32);
                l[qs] = l[qs] * sf[qs] + rs;
                m[qs] = mn[qs];
            }
            // ---- O-rescale for BOTH subtiles (shuffle chains overlap)
#pragma unroll
            for (int qs = 0; qs < 2; ++qs) {
                float sfO[4];
#pragma unroll
                for (int r = 0; r < 4; ++r) sfO[r] = __shfl(sf[qs], l4 * 4 + r);
#pragma unroll
                for (int ht = 0; ht < 4; ++ht)
#pragma unroll
                    for (int r = 0; r < 4; ++r) O[qs][ht][r] *= sfO[r];
            }

            // ---- Ps roundtrip + PV, per qs (shared Ps; in-wave DS order)
#pragma unroll
            for (int qs = 0; qs < 2; ++qs) {
#pragma unroll
                for (int nt = 0; nt < 4; ++nt)
                    *(f16x4*)&Ps[wid][l15][nt * 16 + l4 * 4] = pv[qs][nt];
                const f16x8 pf0 = *(const f16x8*)&Ps[wid][l15][l4 * 8];
                const f16x8 pf1 = *(const f16x8*)&Ps[wid][l15][32 + l4 * 8];
#pragma unroll
                for (int ht = 0; ht < 4; ++ht) {
                    O[qs][ht] = __builtin_amdgcn_mfma_f32_16x16x32_f16(pf0, vf[ht][0], O[qs][ht], 0, 0, 0);
                    O[qs][ht] = __builtin_amdgcn_mfma_f32_16x16x32_f16(pf1, vf[ht][1], O[qs][ht], 0, 0, 0);
                }
            }
        }

        if (more) {
            const int nxt = cur ^ 1;
            *(f16x8*)&Ks[nxt][r0][c0b]      = sk0;
            *(f16x8*)&Ks[nxt][r0 + 32][c0b] = sk1;
            *(f16x8*)&Vs[nxt][r0][c0b]      = sv0;
            *(f16x8*)&Vs[nxt][r0 + 32][c0b] = sv1;
        }
        cur ^= 1;
    }

    // ---- epilogue: transport m/l to D-layout
    float mD[2][4], lD[2][4];
#pragma unroll
    for (int qs = 0; qs < 2; ++qs)
#pragma unroll
        for (int r = 0; r < 4; ++r) {
            mD[qs][r] = __shfl(m[qs], l4 * 4 + r);
            lD[qs][r] = __shfl(l[qs], l4 * 4 + r);
        }

    if (nc == 1) {
#pragma unroll
        for (int qs = 0; qs < 2; ++qs)
#pragma unroll
            for (int r = 0; r < 4; ++r) {
                const float inv = 1.f / lD[qs][r];
                const size_t row = bt0 + qbw + qs * 16 + l4 * 4 + r;
#pragma unroll
                for (int ht = 0; ht < 4; ++ht)
                    out[row * H_ + ht * 16 + l15] = O[qs][ht][r] * inv;
            }
    } else {
        const int slot = b * 144 + j;
#pragma unroll
        for (int qs = 0; qs < 2; ++qs) {
#pragma unroll
            for (int r = 0; r < 4; ++r) {
                const int grow = wid * 32 + qs * 16 + l4 * 4 + r;
#pragma unroll
                for (int ht = 0; ht < 4; ++ht)
                    Op[(size_t)slot * 8192 + grow * 64 + ht * 16 + l15] =
                        (_Float16)O[qs][ht][r];
            }
            if (l4 == 0) {
                const int grow = wid * 32 + qs * 16 + l15;
                Mlp[(size_t)slot * 256 + grow]       = m[qs];
                Mlp[(size_t)slot * 256 + 128 + grow] = l[qs];
            }
        }
    }
}

// ---------------------------------------------------------------------------
// Merge partial chunks for 128-row q-tiles with nc>=2 (qt >= 4).
// Grid 112 = 4 b x 28 qt.
// ---------------------------------------------------------------------------
__global__ __launch_bounds__(256) void attn_merge(
    const _Float16* __restrict__ Op,
    const float* __restrict__ Mlp,
    float* __restrict__ out)
{
    const int b  = blockIdx.x / 28;
    const int qt = 4 + (blockIdx.x - b * 28);
    const int k  = qt >> 2;
    const int g  = k + 1;                              // chunks: 2..8
    const int jstart = 2 * k * (k + 1) + (qt - 4 * k) * (k + 1);
    const int slot0  = b * 144 + jstart;

    const int tid  = threadIdx.x;
    const int colb = (tid & 7) * 8;

    for (int it = 0; it < 4; ++it) {
        const int row = it * 32 + (tid >> 3);
        float mf = -1e30f;
        for (int cc = 0; cc < g; ++cc)
            mf = fmaxf(mf, Mlp[(size_t)(slot0 + cc) * 256 + row]);
        float denom = 0.f;
        float acc[8];
#pragma unroll
        for (int jj = 0; jj < 8; ++jj) acc[jj] = 0.f;
        for (int cc = 0; cc < g; ++cc) {
            const float a = __expf(Mlp[(size_t)(slot0 + cc) * 256 + row] - mf);
            denom += a * Mlp[(size_t)(slot0 + cc) * 256 + 128 + row];
            const f16x8 o = *(const f16x8*)&Op[(size_t)(slot0 + cc) * 8192 + row * 64 + colb];
#pragma unroll
            for (int jj = 0; jj < 8; ++jj) acc[jj] += a * (float)o[jj];
        }
        const float inv = 1.f / denom;
        float* dst = &out[((size_t)b * T_ + (qt << 7) + row) * H_ + colb];
        float4 o0 = { acc[0] * inv, acc[1] * inv, acc[2] * inv, acc[3] * inv };
        float4 o1 = { acc[4] * inv, acc[5] * inv, acc[6] * inv, acc[7] * inv };
        *(float4*)dst = o0;
        *(float4*)(dst + 4) = o1;
    }
}

extern "C" void kernel_launch(void* const* d_in, const int* in_sizes, int n_in,
                              void* d_out, int out_size, void* d_ws, size_t ws_size,
                              hipStream_t stream) {
    const float* x  = (const float*)d_in[0];
    const float* Wk = (const float*)d_in[1];
    const float* Wq = (const float*)d_in[2];
    const float* Wv = (const float*)d_in[3];
    float* out = (float*)d_out;

    _Float16* qh  = (_Float16*)d_ws;                 // [B*T][H] (scaled)
    _Float16* kh  = qh + (size_t)BT_ * H_;           // [B*T][H]
    _Float16* vtt = kh + (size_t)BT_ * H_;           // [BT/64 tiles][64 h][64 s]
    _Float16* Wt  = vtt + (size_t)BT_ * H_;          // [192][768]
    _Float16* Op  = Wt + (size_t)192 * C_;           // 576 slots x [128][64] f16
    float*    Mlp = (float*)(Op + (size_t)576 * 8192);   // 576 x (m[128],l[128])

    wt_cast<<<dim3(48), dim3(256), 0, stream>>>(Wk, Wq, Wv, Wt);
    qkv_gemm<<<dim3(512), dim3(256), 0, stream>>>(x, Wt, qh, kh, vtt);
    attn<<<dim3(576), dim3(256), 0, stream>>>(qh, kh, vtt, out, Op, Mlp);
    attn_merge<<<dim3(112), dim3(256), 0, stream>>>(Op, Mlp, out);
}

// Round 26
// 57.878 us; speedup vs baseline: 1.2329x; 1.2255x over previous
//
#include <hip/hip_runtime.h>

typedef _Float16 f16x8 __attribute__((ext_vector_type(8)));
typedef _Float16 f16x4 __attribute__((ext_vector_type(4)));
typedef float    f32x4 __attribute__((ext_vector_type(4)));

#define B_ 4
#define T_ 4096
#define C_ 768
#define H_ 64
#define BT_ (B_ * T_)
#define SCALE 0.03608439182435161f   // 768^-0.5

// ---------------------------------------------------------------------------
// W transpose+cast: Wt f16 [192][768] = [Wq^T | Wk^T | Wv^T] rows. 48 blocks.
// ---------------------------------------------------------------------------
__global__ __launch_bounds__(256) void wt_cast(
    const float* __restrict__ Wk,
    const float* __restrict__ Wq,
    const float* __restrict__ Wv,
    _Float16* __restrict__ Wt)
{
    __shared__ float Ws[16][192];
    const int tid = threadIdx.x;
    const int k0  = blockIdx.x * 16;
    for (int i = tid; i < 16 * 64; i += 256) {
        const int r = i >> 6, c = i & 63;
        Ws[r][c]       = Wq[(size_t)(k0 + r) * H_ + c];
        Ws[r][64 + c]  = Wk[(size_t)(k0 + r) * H_ + c];
        Ws[r][128 + c] = Wv[(size_t)(k0 + r) * H_ + c];
    }
    __syncthreads();
    for (int i = tid; i < 384; i += 256) {
        const int n = i >> 1, c8 = (i & 1) * 8;
        f16x8 o;
#pragma unroll
        for (int jj = 0; jj < 8; ++jj) o[jj] = (_Float16)Ws[c8 + jj][n];
        *(f16x8*)&Wt[(size_t)n * C_ + k0 + c8] = o;
    }
}

// ---------------------------------------------------------------------------
// QKV projection as MFMA GEMM: [16384 x 768] * [768 x 192].
// Double-buffered T14 async-split (round-14 win). BM=32, 256 threads,
// grid 512 (round-21's BM=64 regressed — do not re-apply).
// ---------------------------------------------------------------------------
__global__ __launch_bounds__(256, 2) void qkv_gemm(
    const float* __restrict__ x,
    const _Float16* __restrict__ Wt,
    _Float16* __restrict__ qh,
    _Float16* __restrict__ kh,
    _Float16* __restrict__ vtt)
{
    __shared__ _Float16 Ah[2][32][72];
    __shared__ _Float16 Bh[2][192][72];

    const int tid  = threadIdx.x;
    const int lane = tid & 63;
    const int w    = tid >> 6;
    const int l15  = lane & 15;
    const int l4   = lane >> 4;
    const int mbase = blockIdx.x * 32;

    const int arow = tid >> 3;
    const int acb  = (tid & 7) * 8;
    const float* asrc = &x[(size_t)(mbase + arow) * C_ + acb];

    f32x4 acc[2][3];
#pragma unroll
    for (int mr = 0; mr < 2; ++mr)
#pragma unroll
        for (int j = 0; j < 3; ++j) acc[mr][j] = (f32x4){0.f, 0.f, 0.f, 0.f};

    {   // prologue: stage k-slab 0 into buffer 0
        const float4 x0 = *(const float4*)(asrc);
        const float4 x1 = *(const float4*)(asrc + 4);
        f16x8 a = { (_Float16)x0.x, (_Float16)x0.y, (_Float16)x0.z, (_Float16)x0.w,
                    (_Float16)x1.x, (_Float16)x1.y, (_Float16)x1.z, (_Float16)x1.w };
        *(f16x8*)&Ah[0][arow][acb] = a;
#pragma unroll
        for (int r = 0; r < 6; ++r) {
            const int idx = tid + r * 256;
            const int n = idx >> 3, c8 = (idx & 7) * 8;
            *(f16x8*)&Bh[0][n][c8] = *(const f16x8*)&Wt[(size_t)n * C_ + c8];
        }
    }

    for (int it = 0; it < 12; ++it) {
        __syncthreads();                 // buf[cur] staged & visible
        const int cur = it & 1;
        const bool more = (it + 1 < 12);

        // ---- issue stage loads for slab it+1 (LDS writes after compute)
        f16x8 sa;
        f16x8 sb[6];
        if (more) {
            const int k0n = (it + 1) * 64;
            const float4 x0 = *(const float4*)(asrc + k0n);
            const float4 x1 = *(const float4*)(asrc + k0n + 4);
            sa = (f16x8){ (_Float16)x0.x, (_Float16)x0.y, (_Float16)x0.z, (_Float16)x0.w,
                          (_Float16)x1.x, (_Float16)x1.y, (_Float16)x1.z, (_Float16)x1.w };
#pragma unroll
            for (int r = 0; r < 6; ++r) {
                const int idx = tid + r * 256;
                const int n = idx >> 3, c8 = (idx & 7) * 8;
                sb[r] = *(const f16x8*)&Wt[(size_t)n * C_ + k0n + c8];
            }
        }
        __builtin_amdgcn_sched_barrier(0);   // pin load issue before compute

        // ---- compute slab it from buf[cur]
#pragma unroll
        for (int kk = 0; kk < 2; ++kk) {
            f16x8 af0 = *(const f16x8*)&Ah[cur][l15][kk * 32 + l4 * 8];
            f16x8 af1 = *(const f16x8*)&Ah[cur][16 + l15][kk * 32 + l4 * 8];
#pragma unroll
            for (int j = 0; j < 3; ++j) {
                const f16x8 bf =
                    *(const f16x8*)&Bh[cur][w * 48 + j * 16 + l15][kk * 32 + l4 * 8];
                acc[0][j] = __builtin_amdgcn_mfma_f32_16x16x32_f16(af0, bf, acc[0][j], 0, 0, 0);
                acc[1][j] = __builtin_amdgcn_mfma_f32_16x16x32_f16(af1, bf, acc[1][j], 0, 0, 0);
            }
        }

        // ---- write staged slab into the other buffer (vmcnt waits here)
        if (more) {
            const int nxt = cur ^ 1;
            *(f16x8*)&Ah[nxt][arow][acb] = sa;
#pragma unroll
            for (int r = 0; r < 6; ++r) {
                const int idx = tid + r * 256;
                const int n = idx >> 3, c8 = (idx & 7) * 8;
                *(f16x8*)&Bh[nxt][n][c8] = sb[r];
            }
        }
    }

#pragma unroll
    for (int mr = 0; mr < 2; ++mr) {
        const size_t row0 = mbase + mr * 16 + l4 * 4;
#pragma unroll
        for (int j = 0; j < 3; ++j) {
            const int gcol = w * 48 + j * 16;
            if (gcol < 64) {
                const int h = gcol + l15;
#pragma unroll
                for (int r = 0; r < 4; ++r)
                    qh[(row0 + r) * H_ + h] = (_Float16)(acc[mr][j][r] * SCALE);
            } else if (gcol < 128) {
                const int h = gcol - 64 + l15;
#pragma unroll
                for (int r = 0; r < 4; ++r)
                    kh[(row0 + r) * H_ + h] = (_Float16)acc[mr][j][r];
            } else {
                const int h = gcol - 128 + l15;
                f16x4 o = { (_Float16)acc[mr][j][0], (_Float16)acc[mr][j][1],
                            (_Float16)acc[mr][j][2], (_Float16)acc[mr][j][3] };
                *(f16x4*)&vtt[((row0 >> 6) << 12) + (h << 6) + (row0 & 63)] = o;
            }
        }
    }
}

// ---------------------------------------------------------------------------
// Flash attention — best measured configuration (rounds 20/23/25,
// 70.93-71.10 us total). LDS-staged double-buffered K/V, T14 async-split
// staging, chunks of <=8 kv-tiles -> 576 blocks heavy-first, swapped-QK
// lane-local softmax, BOTH q-subtile chains hoisted for ILP overlap.
// NOTE: launch_bounds min-waves/EU stays 2 (round-5 spill regression).
// ---------------------------------------------------------------------------
__global__ __launch_bounds__(256, 2) void attn(
    const _Float16* __restrict__ qh,
    const _Float16* __restrict__ kh,
    const _Float16* __restrict__ vtt,
    float* __restrict__ out,
    _Float16* __restrict__ Op,
    float* __restrict__ Mlp)
{
    __shared__ _Float16 Ks[2][64][72];   // [buf][s_local][h]  (+8 pad)
    __shared__ _Float16 Vs[2][64][72];   // [buf][h][s_local]
    __shared__ _Float16 Ps[4][16][72];   // per-wave P layout shuffle

    const int b = blockIdx.x / 144;
    const int j = 143 - (blockIdx.x - b * 144);   // heavy chunks first
    int k = 0;
    while (k < 7 && j >= 2 * (k + 1) * (k + 2)) ++k;
    const int local = j - 2 * k * (k + 1);
    const int qt = 4 * k + local / (k + 1);       // 128-row q-tile id
    const int c  = local - (local / (k + 1)) * (k + 1);
    const int nc = k + 1;
    const int qb = qt << 7;
    const int NT = 2 * qt + 2;                    // kv tiles (64 each)
    const int t0 = c * 8;
    const int t1 = min(NT, t0 + 8);

    const int tid  = threadIdx.x;
    const int lane = tid & 63;
    const int wid  = tid >> 6;
    const int l15  = lane & 15;
    const int l4   = lane >> 4;
    const size_t bt0 = (size_t)b * T_;
    const int qbw = qb + wid * 32;                // wave's 32 q-rows
    const int tmaxw = 2 * qt + (wid >> 1);        // last tile this wave needs

    f16x8 qf[2][2];
#pragma unroll
    for (int qs = 0; qs < 2; ++qs) {
        const size_t qrow = bt0 + qbw + qs * 16 + l15;
        qf[qs][0] = *(const f16x8*)&qh[qrow * H_ + l4 * 8];
        qf[qs][1] = *(const f16x8*)&qh[qrow * H_ + 32 + l4 * 8];
    }

    const int r0  = tid >> 3;
    const int c0b = (tid & 7) * 8;

    {   // prologue: stage tile t0 into buffer 0
        const size_t gb = (size_t)(bt0 + (t0 << 6)) * H_;
        *(f16x8*)&Ks[0][r0][c0b]      = *(const f16x8*)&kh[gb + r0 * 64 + c0b];
        *(f16x8*)&Ks[0][r0 + 32][c0b] = *(const f16x8*)&kh[gb + (r0 + 32) * 64 + c0b];
        *(f16x8*)&Vs[0][r0][c0b]      = *(const f16x8*)&vtt[gb + r0 * 64 + c0b];
        *(f16x8*)&Vs[0][r0 + 32][c0b] = *(const f16x8*)&vtt[gb + (r0 + 32) * 64 + c0b];
    }

    f32x4 O[2][4];
#pragma unroll
    for (int qs = 0; qs < 2; ++qs)
#pragma unroll
        for (int ht = 0; ht < 4; ++ht) O[qs][ht] = (f32x4){0.f, 0.f, 0.f, 0.f};
    float m[2] = {-1e30f, -1e30f};
    float l[2] = {0.f, 0.f};

    int cur = 0;
    for (int t = t0; t < t1; ++t) {
        __syncthreads();

        // issue stage loads for t+1 (written to LDS after compute)
        f16x8 sk0, sk1, sv0, sv1;
        const bool more = (t + 1 < t1);
        if (more) {
            const size_t gb = (size_t)(bt0 + ((t + 1) << 6)) * H_;
            sk0 = *(const f16x8*)&kh[gb + r0 * 64 + c0b];
            sk1 = *(const f16x8*)&kh[gb + (r0 + 32) * 64 + c0b];
            sv0 = *(const f16x8*)&vtt[gb + r0 * 64 + c0b];
            sv1 = *(const f16x8*)&vtt[gb + (r0 + 32) * 64 + c0b];
        }
        __builtin_amdgcn_sched_barrier(0);

        if (t <= tmaxw) {
            const int kb = t << 6;
            f16x8 kf[4][2], vf[4][2];
#pragma unroll
            for (int nt = 0; nt < 4; ++nt)
#pragma unroll
                for (int hf = 0; hf < 2; ++hf)
                    kf[nt][hf] = *(const f16x8*)&Ks[cur][nt * 16 + l15][hf * 32 + l4 * 8];
#pragma unroll
            for (int ht = 0; ht < 4; ++ht)
#pragma unroll
                for (int cc = 0; cc < 2; ++cc)
                    vf[ht][cc] = *(const f16x8*)&Vs[cur][ht * 16 + l15][cc * 32 + l4 * 8];

            const bool needMask = (kb + 63 > qbw);

            // ---- QK for BOTH q-subtiles: 16 independent MFMAs
            f32x4 st[2][4];
#pragma unroll
            for (int qs = 0; qs < 2; ++qs)
#pragma unroll
                for (int nt = 0; nt < 4; ++nt) {
                    f32x4 z = (f32x4){0.f, 0.f, 0.f, 0.f};
                    z = __builtin_amdgcn_mfma_f32_16x16x32_f16(kf[nt][0], qf[qs][0], z, 0, 0, 0);
                    st[qs][nt] = __builtin_amdgcn_mfma_f32_16x16x32_f16(kf[nt][1], qf[qs][1], z, 0, 0, 0);
                }
            if (needMask) {
#pragma unroll
                for (int qs = 0; qs < 2; ++qs) {
                    const int qpos = qbw + qs * 16 + l15;
                    const int sbase = kb + l4 * 4;
#pragma unroll
                    for (int nt = 0; nt < 4; ++nt)
#pragma unroll
                        for (int r = 0; r < 4; ++r)
                            if (sbase + nt * 16 + r > qpos) st[qs][nt][r] = -1e30f;
                }
            }

            // ---- softmax for BOTH subtiles (independent chains overlap)
            float mn[2], sf[2];
            f16x4 pv[2][4];
#pragma unroll
            for (int qs = 0; qs < 2; ++qs) {
                float mx = st[qs][0][0];
#pragma unroll
                for (int nt = 0; nt < 4; ++nt)
#pragma unroll
                    for (int r = 0; r < 4; ++r) mx = fmaxf(mx, st[qs][nt][r]);
                mx = fmaxf(mx, __shfl_xor(mx, 16));
                mx = fmaxf(mx, __shfl_xor(mx, 32));
                mn[qs] = fmaxf(m[qs], mx);
            }
#pragma unroll
            for (int qs = 0; qs < 2; ++qs) {
                sf[qs] = __expf(m[qs] - mn[qs]);
                float rs = 0.f;
#pragma unroll
                for (int nt = 0; nt < 4; ++nt)
#pragma unroll
                    for (int r = 0; r < 4; ++r) {
                        const float p = __expf(st[qs][nt][r] - mn[qs]);
                        rs += p;
                        pv[qs][nt][r] = (_Float16)p;
                    }
                rs += __shfl_xor(rs, 16);
                rs += __shfl_xor(rs, 32);
                l[qs] = l[qs] * sf[qs] + rs;
                m[qs] = mn[qs];
            }
            // ---- O-rescale for BOTH subtiles (shuffle chains overlap)
#pragma unroll
            for (int qs = 0; qs < 2; ++qs) {
                float sfO[4];
#pragma unroll
                for (int r = 0; r < 4; ++r) sfO[r] = __shfl(sf[qs], l4 * 4 + r);
#pragma unroll
                for (int ht = 0; ht < 4; ++ht)
#pragma unroll
                    for (int r = 0; r < 4; ++r) O[qs][ht][r] *= sfO[r];
            }

            // ---- Ps roundtrip + PV, per qs (shared Ps; in-wave DS order)
#pragma unroll
            for (int qs = 0; qs < 2; ++qs) {
#pragma unroll
                for (int nt = 0; nt < 4; ++nt)
                    *(f16x4*)&Ps[wid][l15][nt * 16 + l4 * 4] = pv[qs][nt];
                const f16x8 pf0 = *(const f16x8*)&Ps[wid][l15][l4 * 8];
                const f16x8 pf1 = *(const f16x8*)&Ps[wid][l15][32 + l4 * 8];
#pragma unroll
                for (int ht = 0; ht < 4; ++ht) {
                    O[qs][ht] = __builtin_amdgcn_mfma_f32_16x16x32_f16(pf0, vf[ht][0], O[qs][ht], 0, 0, 0);
                    O[qs][ht] = __builtin_amdgcn_mfma_f32_16x16x32_f16(pf1, vf[ht][1], O[qs][ht], 0, 0, 0);
                }
            }
        }

        if (more) {
            const int nxt = cur ^ 1;
            *(f16x8*)&Ks[nxt][r0][c0b]      = sk0;
            *(f16x8*)&Ks[nxt][r0 + 32][c0b] = sk1;
            *(f16x8*)&Vs[nxt][r0][c0b]      = sv0;
            *(f16x8*)&Vs[nxt][r0 + 32][c0b] = sv1;
        }
        cur ^= 1;
    }

    // ---- epilogue: transport m/l to D-layout
    float mD[2][4], lD[2][4];
#pragma unroll
    for (int qs = 0; qs < 2; ++qs)
#pragma unroll
        for (int r = 0; r < 4; ++r) {
            mD[qs][r] = __shfl(m[qs], l4 * 4 + r);
            lD[qs][r] = __shfl(l[qs], l4 * 4 + r);
        }

    if (nc == 1) {
#pragma unroll
        for (int qs = 0; qs < 2; ++qs)
#pragma unroll
            for (int r = 0; r < 4; ++r) {
                const float inv = 1.f / lD[qs][r];
                const size_t row = bt0 + qbw + qs * 16 + l4 * 4 + r;
#pragma unroll
                for (int ht = 0; ht < 4; ++ht)
                    out[row * H_ + ht * 16 + l15] = O[qs][ht][r] * inv;
            }
    } else {
        const int slot = b * 144 + j;
#pragma unroll
        for (int qs = 0; qs < 2; ++qs) {
#pragma unroll
            for (int r = 0; r < 4; ++r) {
                const int grow = wid * 32 + qs * 16 + l4 * 4 + r;
#pragma unroll
                for (int ht = 0; ht < 4; ++ht)
                    Op[(size_t)slot * 8192 + grow * 64 + ht * 16 + l15] =
                        (_Float16)O[qs][ht][r];
            }
            if (l4 == 0) {
                const int grow = wid * 32 + qs * 16 + l15;
                Mlp[(size_t)slot * 256 + grow]       = m[qs];
                Mlp[(size_t)slot * 256 + 128 + grow] = l[qs];
            }
        }
    }
}

// ---------------------------------------------------------------------------
// Merge partial chunks for 128-row q-tiles with nc>=2 (qt >= 4).
// THIS ROUND: it-loop flattened into the grid — 448 blocks = 4 b x 28 qt x
// 4 row-groups (was 112 blocks x 4 serial iterations; 0.44 blocks/CU left
// most CUs idle and serialized 4 latency chains per block).
// ---------------------------------------------------------------------------
__global__ __launch_bounds__(256) void attn_merge(
    const _Float16* __restrict__ Op,
    const float* __restrict__ Mlp,
    float* __restrict__ out)
{
    const int idx = blockIdx.x;
    const int it  = idx & 3;                           // row group 0..3
    const int bq  = idx >> 2;                          // 0..111
    const int b   = bq / 28;
    const int qt  = 4 + (bq - b * 28);
    const int k   = qt >> 2;
    const int g   = k + 1;                             // chunks: 2..8
    const int jstart = 2 * k * (k + 1) + (qt - 4 * k) * (k + 1);
    const int slot0  = b * 144 + jstart;

    const int tid  = threadIdx.x;
    const int colb = (tid & 7) * 8;
    const int row  = it * 32 + (tid >> 3);

    float mf = -1e30f;
    for (int cc = 0; cc < g; ++cc)
        mf = fmaxf(mf, Mlp[(size_t)(slot0 + cc) * 256 + row]);
    float denom = 0.f;
    float acc[8];
#pragma unroll
    for (int jj = 0; jj < 8; ++jj) acc[jj] = 0.f;
    for (int cc = 0; cc < g; ++cc) {
        const float a = __expf(Mlp[(size_t)(slot0 + cc) * 256 + row] - mf);
        denom += a * Mlp[(size_t)(slot0 + cc) * 256 + 128 + row];
        const f16x8 o = *(const f16x8*)&Op[(size_t)(slot0 + cc) * 8192 + row * 64 + colb];
#pragma unroll
        for (int jj = 0; jj < 8; ++jj) acc[jj] += a * (float)o[jj];
    }
    const float inv = 1.f / denom;
    float* dst = &out[((size_t)b * T_ + (qt << 7) + row) * H_ + colb];
    float4 o0 = { acc[0] * inv, acc[1] * inv, acc[2] * inv, acc[3] * inv };
    float4 o1 = { acc[4] * inv, acc[5] * inv, acc[6] * inv, acc[7] * inv };
    *(float4*)dst = o0;
    *(float4*)(dst + 4) = o1;
}

extern "C" void kernel_launch(void* const* d_in, const int* in_sizes, int n_in,
                              void* d_out, int out_size, void* d_ws, size_t ws_size,
                              hipStream_t stream) {
    const float* x  = (const float*)d_in[0];
    const float* Wk = (const float*)d_in[1];
    const float* Wq = (const float*)d_in[2];
    const float* Wv = (const float*)d_in[3];
    float* out = (float*)d_out;

    _Float16* qh  = (_Float16*)d_ws;                 // [B*T][H] (scaled)
    _Float16* kh  = qh + (size_t)BT_ * H_;           // [B*T][H]
    _Float16* vtt = kh + (size_t)BT_ * H_;           // [BT/64 tiles][64 h][64 s]
    _Float16* Wt  = vtt + (size_t)BT_ * H_;          // [192][768]
    _Float16* Op  = Wt + (size_t)192 * C_;           // 576 slots x [128][64] f16
    float*    Mlp = (float*)(Op + (size_t)576 * 8192);   // 576 x (m[128],l[128])

    wt_cast<<<dim3(48), dim3(256), 0, stream>>>(Wk, Wq, Wv, Wt);
    qkv_gemm<<<dim3(512), dim3(256), 0, stream>>>(x, Wt, qh, kh, vtt);
    attn<<<dim3(576), dim3(256), 0, stream>>>(qh, kh, vtt, out, Op, Mlp);
    attn_merge<<<dim3(448), dim3(256), 0, stream>>>(Op, Mlp, out);
}